// Round 3
// baseline (327.084 us; speedup 1.0000x reference)
//
#include <hip/hip_runtime.h>
#include <math.h>

// Problem constants (B=16, T=4096, D=64, K=1024)
#define NROWS    65536      // B*T
#define DD       64
#define KK       1024
#define LOSS_OFF 4194304
#define IDX_OFF  4194305    // idx written as float32 (harness reads flat fp32)

typedef float vf16 __attribute__((ext_vector_type(16)));

// Scalar-pipe load of 16 floats from a wave-uniform address. The compiler's
// waitcnt pass cannot see inside the asm, so completion is enforced by
// swait0(), whose "+s" tie makes every consumer data-dependent on the wait.
__device__ __forceinline__ void sload16(vf16& dst, const float* p) {
    asm volatile("s_load_dwordx16 %0, %1, 0x0" : "=s"(dst) : "s"(p));
}
__device__ __forceinline__ void swait0(vf16& v) {
    asm volatile("s_waitcnt lgkmcnt(0)" : "+s"(v));
}

// numpy pairwise_sum (n=64: 8 accumulators, fixed combine tree) over
// fl(v[i]^2); contract(off) keeps square rounded before add. Verified
// bit-exact (rounds 1-2, absmax 0.0). Do not touch.
__device__ __forceinline__ float np_sumsq64(const float* v) {
#pragma clang fp contract(off)
    float r[8];
#pragma unroll
    for (int j = 0; j < 8; ++j) r[j] = v[j] * v[j];
#pragma unroll
    for (int i = 8; i < 64; i += 8) {
#pragma unroll
        for (int j = 0; j < 8; ++j) r[j] += v[i + j] * v[i + j];
    }
    return ((r[0] + r[1]) + (r[2] + r[3])) + ((r[4] + r[5]) + (r[6] + r[7]));
}

// Kernel 1: per-code norms ||e_k||^2 (numpy order) + zero the fp32 loss slot
// (stream-ordered before vq_main's atomics; d_out is poisoned 0xAA).
__global__ void vq_norms(const float* __restrict__ emb,
                         float* __restrict__ bn,
                         float* __restrict__ out) {
    const int k = blockIdx.x * blockDim.x + threadIdx.x;
    if (k == 0) out[LOSS_OFF] = 0.0f;
    if (k >= KK) return;
    float e[DD];
    const float* ep = emb + (size_t)k * DD;
#pragma unroll
    for (int d = 0; d < DD; d += 4) {
        const float4 v = *reinterpret_cast<const float4*>(ep + d);
        e[d] = v.x; e[d + 1] = v.y; e[d + 2] = v.z; e[d + 3] = v.w;
    }
    bn[k] = np_sumsq64(e);
}

// Kernel 2: block = 4 waves over the SAME 64 rows; wave w scans code slice
// [w*256,(w+1)*256). lane = row; zr in VGPRs. The e stream is wave-uniform,
// so it runs on the SCALAR pipe: ping-pong s_load_dwordx16 buffers A/B,
// always s_waitcnt lgkmcnt(0) (safe vs any compiler SMEM; SMEM completes
// out of order so partial counts would be unsafe anyway). The fmaf chain
// reads e directly from SGPRs (v_fmac v,s,v — 1 SGPR src is legal), so the
// vector pipe is ~pure fmac: no per-lane e loads, no vector address math.
// waves_per_eu(2,4): the MAX is what stops the allocator from targeting
// 8 waves/EU (=64-VGPR budget) as in rounds 1-2 — zr must stay resident.
// dist chain bit-identical to verified rounds: t=a+bn[k]; s=fmaf(-2,dot,t);
// dot = ascending-d fmaf chain; ascending-k strict < argmin.
__global__ __launch_bounds__(256) __attribute__((amdgpu_waves_per_eu(2, 4)))
void vq_main(const float* __restrict__ z, const float* __restrict__ emb,
             const float* __restrict__ bn, float* __restrict__ out) {
    const int tid  = threadIdx.x;
    const int lane = tid & 63;
    const int wv   = __builtin_amdgcn_readfirstlane(tid) >> 6;   // 0..3
    const int row  = blockIdx.x * 64 + lane;

    const int k0 = wv * (KK / 4);
    const float* pk    = emb + (size_t)k0 * DD;       // uniform slice base
    const float* plast = pk + 1023 * 16;              // last 16-float chunk
    const float* pl    = pk;

    vf16 A, B;
    sload16(A, pl); pl += 16;   // chunk 0 in flight
    sload16(B, pl); pl += 16;   // chunk 1 in flight

    // Overlap prime-load latency with the zr VMEM loads + norm.
    float zr[DD];
    const float* zp = z + (size_t)row * DD;
#pragma unroll
    for (int d = 0; d < DD; d += 4) {
        const float4 v = *reinterpret_cast<const float4*>(zp + d);
        zr[d] = v.x; zr[d + 1] = v.y; zr[d + 2] = v.z; zr[d + 3] = v.w;
    }
    const float a = np_sumsq64(zr);   // ||z_row||^2, numpy bit-order

    swait0(A);                        // lgkmcnt(0): A and B both ready

    float best = 3.402823466e+38f;
    int bid = 0;

#define ISSUE(DST) { const float* pi = (pl <= plast) ? pl : plast; \
                     sload16(DST, pi); pl += 16; }

    for (int k = k0; k < k0 + KK / 4; ++k) {
        float dot = 0.f;
        // Invariant at loop top: A = chunk 4j (ready), B = chunk 4j+1
        // (ready or in flight).
#pragma unroll
        for (int i = 0; i < 16; ++i) dot = fmaf(zr[i],      A[i], dot);
        swait0(B); ISSUE(A);          // A <- chunk 4j+2
#pragma unroll
        for (int i = 0; i < 16; ++i) dot = fmaf(zr[16 + i], B[i], dot);
        swait0(A); ISSUE(B);          // B <- chunk 4j+3
#pragma unroll
        for (int i = 0; i < 16; ++i) dot = fmaf(zr[32 + i], A[i], dot);
        swait0(B); ISSUE(A);          // A <- chunk 4(j+1)
#pragma unroll
        for (int i = 0; i < 16; ++i) dot = fmaf(zr[48 + i], B[i], dot);
        swait0(A); ISSUE(B);          // B <- chunk 4(j+1)+1

        const float t = a + bn[k];
        const float s = fmaf(-2.f, dot, t);
        if (s < best) { best = s; bid = k; }
    }
#undef ISSUE

    // Cross-slice argmin combine: ascending slice + strict < == numpy
    // global first-index tie-break (verified rounds 1-2).
    __shared__ float sbest[4][64];
    __shared__ int   sbid[4][64];
    sbest[wv][lane] = best;
    sbid[wv][lane]  = bid;
    __syncthreads();
    if (wv != 0) return;
#pragma unroll
    for (int s = 1; s < 4; ++s) {
        const float b2 = sbest[s][lane];
        const int   i2 = sbid[s][lane];
        if (b2 < best) { best = b2; bid = i2; }
    }

    // Epilogue (wave 0 only; zr still live).
    const float* ep = emb + (size_t)bid * DD;
    float* op = out + (size_t)row * DD;
    double sac = 0.0;
#pragma unroll
    for (int d = 0; d < DD; d += 4) {
        const float4 e4 = *reinterpret_cast<const float4*>(ep + d);
        const float df0 = e4.x - zr[d];
        const float df1 = e4.y - zr[d + 1];
        const float df2 = e4.z - zr[d + 2];
        const float df3 = e4.w - zr[d + 3];
        float4 q;
        q.x = zr[d] + df0;     q.y = zr[d + 1] + df1;
        q.z = zr[d + 2] + df2; q.w = zr[d + 3] + df3;
        *reinterpret_cast<float4*>(op + d) = q;
        sac += (double)(df0 * df0); sac += (double)(df1 * df1);
        sac += (double)(df2 * df2); sac += (double)(df3 * df3);
    }
    out[IDX_OFF + row] = (float)bid;

#pragma unroll
    for (int off = 32; off > 0; off >>= 1) sac += __shfl_down(sac, off, 64);
    // loss = 1.25 * S_total / (T*D); fp32 atomic per block (error ~1e-3,
    // threshold 20.48) — saves the finalize launch.
    if (lane == 0)
        atomicAdd(&out[LOSS_OFF], (float)((1.25 * sac) / 262144.0));
}

extern "C" void kernel_launch(void* const* d_in, const int* in_sizes, int n_in,
                              void* d_out, int out_size, void* d_ws, size_t ws_size,
                              hipStream_t stream) {
    const float* z   = (const float*)d_in[0];   // [16,4096,64] fp32
    const float* emb = (const float*)d_in[1];   // [1024,64] fp32
    float* out = (float*)d_out;                 // zq | loss | idx (flat fp32)

    float* bn = (float*)d_ws;                   // 1024 floats

    vq_norms<<<dim3(KK / 256), dim3(256), 0, stream>>>(emb, bn, out);
    vq_main<<<dim3(NROWS / 64), dim3(256), 0, stream>>>(z, emb, bn, out);
}